// Round 12
// baseline (19.391 us; speedup 1.0000x reference)
//
#include <hip/hip_runtime.h>
#include <math.h>

namespace {
constexpr int P = 4096, O = 32, H = 26, V = 48;
constexpr int GPITCH = 28;            // Gram row stride (floats); 112B rows, 16B-aligned
constexpr float EPSV = 1e-4f;         // strict < EPSV == numpy's (f32 <= 1e-4 f64)
}

// Packed f32 FMA: D.f32[0,1] = S0[0,1]*S1[0,1] + S2[0,1]  (VOP3P, CDNA4)
__device__ __forceinline__ float2 pk_fma(float2 a, float2 b, float2 c) {
    float2 d;
    asm("v_pk_fma_f32 %0, %1, %2, %3" : "=v"(d) : "v"(a), "v"(b), "v"(c));
    return d;
}
// Written so clang fuses to v_max3_f32.
__device__ __forceinline__ float max3f(float a, float b, float c) {
    return fmaxf(fmaxf(a, b), c);
}

// One thread per (point p, object o).
// Gram trick: Appb[h][j] = s_j - s_h * G[h][j], G = A A^T in LDS.
// s_j keeps the reference's exact rounding (argmax/max_vals/is_neg exact).
// nsh = b - dot == -s_h bitwise, so t_j = pk_fma(nsh, G, s_j) has fmaf
// rounding; psq = nsh^2 * G[h][h]; sqrt once per pass (monotone).
// Face loop stays ROLLED (R10: full unroll -> 256 VGPR + 177MB spill).
__global__ __launch_bounds__(256) void zono_kernel(
    const float* __restrict__ point,   // [P][3]
    const float* __restrict__ hA,      // [O][H][3]
    const float* __restrict__ hb,      // [O][H]
    const float* __restrict__ v1g,     // [O][V][3]
    const float* __restrict__ v2g,     // [O][V][3]
    float* __restrict__ dist_out,      // [P][O]
    float* __restrict__ grad_out)      // [P][O][3]
{
    __shared__ float4 sAb[H];            // {a0,a1,a2,b}
    __shared__ float  sG[H][GPITCH];     // Gram a_h . a_j
    __shared__ float4 sV1[V];            // {v1_0,v1_1,v1_2, inv_den}
    __shared__ float4 sE[V];             // {e0,e1,e2, -(v1.e)*inv_den}

    const int o   = blockIdx.y;
    const int tid = threadIdx.x;

    if (tid < H) {
        const float* a = hA + (o * H + tid) * 3;
        sAb[tid] = make_float4(a[0], a[1], a[2], hb[o * H + tid]);
    } else if (tid >= 32 && tid < 32 + V) {
        const int v = tid - 32;
        const float* A1 = v1g + (o * V + v) * 3;
        const float* A2 = v2g + (o * V + v) * 3;
        const float x0 = A1[0], x1 = A1[1], x2 = A1[2];
        const float e0 = __fsub_rn(A2[0], x0);
        const float e1 = __fsub_rn(A2[1], x1);
        const float e2 = __fsub_rn(A2[2], x2);
        const float den = __fadd_rn(__fadd_rn(__fmul_rn(e0, e0), __fmul_rn(e1, e1)),
                                    __fmul_rn(e2, e2));
        const float inv = __fdiv_rn(1.f, den);
        const float cv  = __fadd_rn(__fadd_rn(__fmul_rn(x0, e0), __fmul_rn(x1, e1)),
                                    __fmul_rn(x2, e2));
        const float nci = -__fmul_rn(cv, inv);
        sV1[v] = make_float4(x0, x1, x2, inv);
        sE[v]  = make_float4(e0, e1, e2, nci);
    }
    __syncthreads();

    // Build Gram table.
    for (int e = tid; e < H * H; e += 256) {
        const int h = e / H;
        const int j = e - h * H;
        const float4 A = sAb[h];
        const float4 B = sAb[j];
        sG[h][j] = __fadd_rn(__fadd_rn(__fmul_rn(A.x, B.x), __fmul_rn(A.y, B.y)),
                             __fmul_rn(A.z, B.z));
    }
    __syncthreads();

    const int p = blockIdx.x * blockDim.x + tid;
    const float p0 = point[p * 3 + 0];
    const float p1 = point[p * 3 + 1];
    const float p2 = point[p * 3 + 2];

    // ---- s_j (exact reference rounding), packed into float2 pairs ----
    float2 s2[13];                       // compile-time indexed only
    float maxv = -INFINITY; int maxi = 0;
    #pragma unroll
    for (int j = 0; j < H; ++j) {
        const float4 ab = sAb[j];
        const float sj = __fsub_rn(
            __fadd_rn(__fadd_rn(__fmul_rn(p0, ab.x), __fmul_rn(p1, ab.y)),
                      __fmul_rn(p2, ab.z)),
            ab.w);
        if (j & 1) s2[j >> 1].y = sj; else s2[j >> 1].x = sj;
        if (sj > maxv) { maxv = sj; maxi = j; }        // first argmax
    }
    const bool is_neg = (maxv <= 0.f);

    // ---- face pass (ROLLED): t_j = pk_fma(nsh, G[h][j], s_j) ----
    float minpsq = INFINITY; int mini = 0;
    for (int h = 0; h < H; ++h) {
        const float4 ab = sAb[h];                       // broadcast LDS read
        const float dot = __fadd_rn(__fadd_rn(__fmul_rn(p0, ab.x),
                                              __fmul_rn(p1, ab.y)),
                                    __fmul_rn(p2, ab.z));
        const float nsh = __fsub_rn(ab.w, dot);         // == -s[h] bitwise
        const float2 nsh2 = make_float2(nsh, nsh);

        const float2* gRow2 = reinterpret_cast<const float2*>(&sG[h][0]);
        float2 t2[13];
        #pragma unroll
        for (int q = 0; q < 13; ++q)
            t2[q] = pk_fma(nsh2, gRow2[q], s2[q]);      // {s-sh*G} pairs

        // max of 26 halves via max3 tree (exact reassociation)
        const float a0 = max3f(t2[0].x, t2[0].y, t2[1].x);
        const float a1 = max3f(t2[1].y, t2[2].x, t2[2].y);
        const float a2 = max3f(t2[3].x, t2[3].y, t2[4].x);
        const float a3 = max3f(t2[4].y, t2[5].x, t2[5].y);
        const float a4 = max3f(t2[6].x, t2[6].y, t2[7].x);
        const float a5 = max3f(t2[7].y, t2[8].x, t2[8].y);
        const float a6 = max3f(t2[9].x, t2[9].y, t2[10].x);
        const float a7 = max3f(t2[10].y, t2[11].x, t2[11].y);
        const float b0 = max3f(a0, a1, a2);
        const float b1 = max3f(a3, a4, a5);
        const float b2 = max3f(a6, a7, t2[12].x);
        const float tmax = fmaxf(max3f(b0, b1, b2), t2[12].y);
        const bool onz = (tmax < EPSV);

        const float psq = __fmul_rn(__fmul_rn(nsh, nsh), sG[h][h]);
        if (onz && psq < minpsq) { minpsq = psq; mini = h; }  // first argmin
    }
    const float minperp = __fsqrt_rn(minpsq);   // monotone: == min of sqrts

    // ---- edge pass: th = fma(p.e, inv, nci); track (ts, idx), q later ----
    float minesq = INFINITY; int midx = 0; float tsm = 0.f;
    #pragma unroll 2
    for (int v = 0; v < V; ++v) {
        const float4 V1 = sV1[v];
        const float4 E  = sE[v];
        const float dpe = __builtin_fmaf(p0, E.x,
                          __builtin_fmaf(p1, E.y, __fmul_rn(p2, E.z)));
        const float th = __builtin_fmaf(dpe, V1.w, E.w);
        const float ts = __builtin_amdgcn_fmed3f(th, 0.f, 1.f);
        const float g0 = __fsub_rn(p0, __builtin_fmaf(ts, E.x, V1.x));
        const float g1 = __fsub_rn(p1, __builtin_fmaf(ts, E.y, V1.y));
        const float g2 = __fsub_rn(p2, __builtin_fmaf(ts, E.z, V1.z));
        const float esq = __builtin_fmaf(g0, g0,
                          __builtin_fmaf(g1, g1, __fmul_rn(g2, g2)));
        if (esq < minesq) { minesq = esq; midx = v; tsm = ts; }
    }
    const float mine = __fsqrt_rn(minesq);      // monotone: == min of sqrts

    // Recompute winner's closest point (deterministic, bitwise equal).
    const float4 V1w = sV1[midx];
    const float4 Ew  = sE[midx];
    const float vm0 = __builtin_fmaf(tsm, Ew.x, V1w.x);
    const float vm1 = __builtin_fmaf(tsm, Ew.y, V1w.y);
    const float vm2 = __builtin_fmaf(tsm, Ew.z, V1w.z);

    // ---- select ----
    const int   fidx = is_neg ? maxi : mini;
    const float4 ga  = sAb[fidx];
    float dist = is_neg ? maxv : minperp;
    float g0 = ga.x, g1 = ga.y, g2 = ga.z;
    if (!is_neg && (mine < dist)) {
        dist = mine;
        g0 = __fdiv_rn(__fsub_rn(p0, vm0), mine);
        g1 = __fdiv_rn(__fsub_rn(p1, vm1), mine);
        g2 = __fdiv_rn(__fsub_rn(p2, vm2), mine);
    }

    const int idx = p * O + o;
    dist_out[idx] = dist;
    grad_out[idx * 3 + 0] = g0;
    grad_out[idx * 3 + 1] = g1;
    grad_out[idx * 3 + 2] = g2;
}

extern "C" void kernel_launch(void* const* d_in, const int* in_sizes, int n_in,
                              void* d_out, int out_size, void* d_ws, size_t ws_size,
                              hipStream_t stream) {
    const float* point = (const float*)d_in[0];
    const float* hA    = (const float*)d_in[1];
    const float* hb    = (const float*)d_in[2];
    const float* v1    = (const float*)d_in[3];
    const float* v2    = (const float*)d_in[4];
    float* out = (float*)d_out;

    dim3 grid(P / 256, O);
    zono_kernel<<<grid, dim3(256), 0, stream>>>(point, hA, hb, v1, v2,
                                                out, out + P * O);
}